// Round 11
// baseline (111.670 us; speedup 1.0000x reference)
//
#include <hip/hip_runtime.h>
#include <math.h>

#define NB 7
#define EPS_ 0.02f
#define ITERS1_ 120   // log-domain phase (R9 logic; mult fast-path EA write)
#define ITERS2_ 80    // multiplicative phase; total 200 == reference count.
// R12/R14: trajectory matching at exactly 200 iterations is mandatory.
// R1: switch@96 FAILED. Switch stays at 120.
// History: R2 57.2 / R4 57.5 / R7 58.4 / R8 61.6 / R9 51.7us dispatch (best;
// bench 110.8, absmax exactly 1.525879e-05). R10 (full multiplicative spine +
// shadow t) FAILED with NaN: long-lived mult state + shadow decoupling is not
// headlessly verifiable. LESSON: only per-iteration-refreshed multiplicative
// values are provable.
// THIS ROUND (R11): R9 with ONE change — fast-path bufEA value computed as
// EA = (e*b2c)*rcp(ss) instead of exp2(t'+cb). e = exp2(q) stays EXACT every
// iteration (no long-lived mult state). NaN-proof by range induction:
// e<=~4, b2c<=2^11, rss<=2^100 (ss window-checked) => EA<=2^113 finite;
// oversized next-row s fails the row window -> exact bufAA rescue.
// t/a updates and all rescue paths R9-verbatim; phase 2 R9-verbatim.
// Perturbation enters only as ulps in s (R3/R5 class): expect absmax
// ~1e-5..2e-4 vs threshold 1.04e-3.
#define TINY_ 1e-40f
#define LOG2E_ 1.4426950408889634f
#define LN2_   0.6931471805599453f

__device__ __forceinline__ float exp2_hw(float x) {
#if __has_builtin(__builtin_amdgcn_exp2f)
    return __builtin_amdgcn_exp2f(x);
#else
    return __expf(x * LN2_);
#endif
}
__device__ __forceinline__ float log2_hw(float x) {
#if __has_builtin(__builtin_amdgcn_logf)
    return __builtin_amdgcn_logf(x);
#else
    return __logf(x) * LOG2E_;
#endif
}
__device__ __forceinline__ float rcp_hw(float x) {
#if __has_builtin(__builtin_amdgcn_rcpf)
    return __builtin_amdgcn_rcpf(x);
#else
    return 1.0f / x;
#endif
}

// ---- DPP helpers (proven in prior rounds) ----
template <int CTRL>
__device__ __forceinline__ float dpp_ident(float identity, float x) {
    return __int_as_float(__builtin_amdgcn_update_dpp(
        __float_as_int(identity), __float_as_int(x), CTRL, 0xF, 0xF, false));
}
__device__ __forceinline__ float readlane63(float x) {
    return __int_as_float(__builtin_amdgcn_readlane(__float_as_int(x), 63));
}
__device__ __forceinline__ float wave_sum_bcast(float s) {
    s += dpp_ident<0x111>(0.f, s);
    s += dpp_ident<0x112>(0.f, s);
    s += dpp_ident<0x114>(0.f, s);
    s += dpp_ident<0x118>(0.f, s);
    s += dpp_ident<0x142>(0.f, s);
    s += dpp_ident<0x143>(0.f, s);
    return readlane63(s);
}
__device__ __forceinline__ float wave_max_bcast(float m) {
    const float NI = __int_as_float(0xff800000);
    m = fmaxf(m, dpp_ident<0x111>(NI, m));
    m = fmaxf(m, dpp_ident<0x112>(NI, m));
    m = fmaxf(m, dpp_ident<0x114>(NI, m));
    m = fmaxf(m, dpp_ident<0x118>(NI, m));
    m = fmaxf(m, dpp_ident<0x142>(NI, m));
    m = fmaxf(m, dpp_ident<0x143>(NI, m));
    return readlane63(m);
}

#define STRIDE_ 9   // 9 coprime 32 -> 2 lanes/bank on row reads/writes (free)

__global__ __launch_bounds__(448) void sinkhorn_kernel(
    const float* __restrict__ theta,  // [64,7]
    const float* __restrict__ phi,    // [7]
    const float* __restrict__ n,      // [64]
    const float* __restrict__ sens,   // [64]
    const float* __restrict__ err,    // [7]
    float* __restrict__ out)          // [64,7]
{
    const int tid  = threadIdx.x;
    const int lane = tid & 63;        // row
    const int wid  = tid >> 6;        // column 0..6 (one wave per column)

    __shared__ float bufEA[2][64 * STRIDE_ + 8];   // ~exp2(t+cb) per cell
    __shared__ float bufAA[2][64 * STRIDE_ + 8];   // a = t+cb per cell (rescue)
    __shared__ float ldsS[8];                      // epilogue column sums

    const float ni = n[lane];
    const float si = sens[lane];
    const float ej = err[wid];
    const float th = theta[lane * NB + wid];

    // nsum identical in every wave (same per-lane ni, same tree).
    const float nsum   = wave_sum_bcast(ni);
    const float aT     = ni / nsum + TINY_;
    const float log_a2 = log2_hw(aT);

    // softmax(phi): same scalar sequence as R2/R7/R9.
    float t2v0 = phi[0] * LOG2E_, t2v1 = phi[1] * LOG2E_,
          t2v2 = phi[2] * LOG2E_, t2v3 = phi[3] * LOG2E_,
          t2v4 = phi[4] * LOG2E_, t2v5 = phi[5] * LOG2E_,
          t2v6 = phi[6] * LOG2E_;
    float pmax = t2v0;
    pmax = fmaxf(pmax, t2v1); pmax = fmaxf(pmax, t2v2);
    pmax = fmaxf(pmax, t2v3); pmax = fmaxf(pmax, t2v4);
    pmax = fmaxf(pmax, t2v5); pmax = fmaxf(pmax, t2v6);
    float psum = exp2_hw(t2v0 - pmax);
    psum += exp2_hw(t2v1 - pmax); psum += exp2_hw(t2v2 - pmax);
    psum += exp2_hw(t2v3 - pmax); psum += exp2_hw(t2v4 - pmax);
    psum += exp2_hw(t2v5 - pmax); psum += exp2_hw(t2v6 - pmax);
    const float lps  = log2_hw(psum);
    const float myt2 = phi[wid] * LOG2E_;
    const float bTj  = exp2_hw(myt2 - pmax - lps) + TINY_;
    const float lb2j = log2_hw(bTj);
    const float cbj  = lb2j - log_a2;
    const float b2c  = exp2_hw(cbj);    // 2^cb (for the fast-path EA write)

    const float kscale = LOG2E_ / EPS_;
    float t = (th - ni * si * ej) * kscale - lb2j;
    float a = t + cbj;
    float EA = exp2_hw(a);              // initial bufEA value (exact)

    const float LOF = __int_as_float(0x0D800000);  // 2^-100
    const float HIF = __int_as_float(0x71800000);  // 2^+100
    const unsigned LOu = 0x0D800000u, HIu = 0x71800000u;
    const int   base = lane * STRIDE_ + wid;
    const int   rb   = lane * STRIDE_;

    // ---- Phase 1: log-domain, transposed. 1 barrier/iter (parity dbuf). ----
    for (int it = 0; it < ITERS1_; ++it) {
        const int p = it & 1;
        bufEA[p][base] = EA;
        bufAA[p][base] = a;
        __syncthreads();

        const float e0 = bufEA[p][rb + 0], e1 = bufEA[p][rb + 1],
                    e2 = bufEA[p][rb + 2], e3 = bufEA[p][rb + 3],
                    e4 = bufEA[p][rb + 4], e5 = bufEA[p][rb + 5],
                    e6 = bufEA[p][rb + 6];
        const float s = ((e0 + e1) + (e2 + e3)) + ((e4 + e5) + e6);

        // Speculative fast-path L; ballot resolves in parallel, rescue
        // overwrites (R9 scheduling).
        float L = log2_hw(s);
        const bool ok = (s >= LOF) && (s <= HIF);   // NaN/inf -> false
        if (__ballot(ok) != ~0ull) {                // identical in all waves
            const float a0 = bufAA[p][rb + 0], a1 = bufAA[p][rb + 1],
                        a2 = bufAA[p][rb + 2], a3 = bufAA[p][rb + 3],
                        a4 = bufAA[p][rb + 4], a5 = bufAA[p][rb + 5],
                        a6 = bufAA[p][rb + 6];
            const float m = fmaxf(fmaxf(fmaxf(a0, a1), fmaxf(a2, a3)),
                                  fmaxf(fmaxf(a4, a5), a6));
            const float s2 = ((exp2_hw(a0 - m) + exp2_hw(a1 - m))
                            + (exp2_hw(a2 - m) + exp2_hw(a3 - m)))
                           + ((exp2_hw(a4 - m) + exp2_hw(a5 - m))
                            + exp2_hw(a6 - m));
            L = m + log2_hw(s2);
        }

        const float q = t - L;
        const float e = exp2_hw(q);                 // EXACT every iteration
        const float ss = wave_sum_bcast(e);         // wave-uniform (SGPR)
        const float rss = rcp_hw(ss);
        const float eb  = e * b2c;                  // issued during DPP/rcp

        // Speculative fast-path L2; uint window check on the SGPR value.
        float L2 = log2_hw(ss);
        const unsigned ssu = __float_as_uint(ss);
        if (ssu < LOu || ssu > HIu) {               // wave-local rescue
            const float M   = wave_max_bcast(q);
            const float e2  = exp2_hw(q - M);
            const float ss2 = wave_sum_bcast(e2);   // in [1,64]
            L2 = M + log2_hw(ss2);
            t  = q - L2;
            a  = t + cbj;
            EA = exp2_hw(a);                        // exact rebuild (R9 path)
        } else {
            t  = q - L2;                            // shadow for bufAA/switch
            a  = t + cbj;
            EA = eb * rss;   // = exp2(q+cb)/ss up to rcp-ulp; finite by range
        }
    }

    // ---- Switch @120 (R13-validated mechanics): U = 2^t, underflow->0. ----
    float U = exp2_hw(t);
    const float Bj = b2c;

    // ---- Phase 2: multiplicative, transposed (R9-verbatim). ----
    for (int it2 = 0; it2 < ITERS2_; ++it2) {
        const int p = it2 & 1;
        bufEA[p][base] = U * Bj;
        __syncthreads();
        const float p0 = bufEA[p][rb + 0], p1 = bufEA[p][rb + 1],
                    p2 = bufEA[p][rb + 2], p3 = bufEA[p][rb + 3],
                    p4 = bufEA[p][rb + 4], p5 = bufEA[p][rb + 5],
                    p6 = bufEA[p][rb + 6];
        const float s  = ((p0 + p1) + (p2 + p3)) + ((p4 + p5) + p6);
        const float rs = rcp_hw(s);
        const float w  = U * rs;
        const float ss = wave_sum_bcast(w);
        U = w * rcp_hw(ss);
    }

    // ---- Epilogue: P = U*bT; normalize by total (+TINY). ----
    const float pr = U * bTj;
    const float cs = wave_sum_bcast(pr);   // column sum (wave-uniform)
    if (lane == 0) ldsS[wid] = cs;
    __syncthreads();
    const float total = ((ldsS[0] + ldsS[1]) + (ldsS[2] + ldsS[3]))
                      + ((ldsS[4] + ldsS[5]) + ldsS[6]);
    out[lane * NB + wid] = pr * (1.0f / (total + TINY_));
}

extern "C" void kernel_launch(void* const* d_in, const int* in_sizes, int n_in,
                              void* d_out, int out_size, void* d_ws, size_t ws_size,
                              hipStream_t stream) {
    const float* theta = (const float*)d_in[0];
    const float* phi   = (const float*)d_in[1];
    const float* n     = (const float*)d_in[2];
    const float* sens  = (const float*)d_in[3];
    const float* err   = (const float*)d_in[4];
    float* out = (float*)d_out;

    sinkhorn_kernel<<<1, 448, 0, stream>>>(theta, phi, n, sens, err, out);
}

// Round 12
// 109.802 us; speedup vs baseline: 1.0170x; 1.0170x over previous
//
#include <hip/hip_runtime.h>
#include <math.h>

#define NB 7
#define EPS_ 0.02f
#define ITERS1_ 120   // log-domain phase (R2-equivalent logic, transposed)
#define ITERS2_ 80    // multiplicative phase; total 200 == reference count.
// R12/R14: trajectory matching at exactly 200 iterations is mandatory.
// R1: switch@96 FAILED. Switch stays at 120.
// SESSION SUMMARY (final state = R9, the best verified kernel):
//   R2 1-wave log-domain:        57.2us dispatch
//   R4 1-wave mant/exp:          57.5us
//   R7 7-wave transposed log:    58.4us
//   R8 7-wave mant/exp:          61.6us
//   R9 = R7 + speculative log2 + SGPR uint window:  51.7us  <-- THIS KERNEL
//   R10 multiplicative spine + shadow t: NaN FAIL (unprovable invariant)
//   R11 fast-path EA via rcp:    59.5us REGRESSION (unexplained; model gap)
// absmax 1.525879e-05 == bf16 output floor (2^-16), shared by all passing
// variants — uninformative below ~1e-4.
// The kernel is latency-bound: 200 serial iterations x (one cross-thread
// exchange + transcendental chain). Remaining model residual (~830cy/iter
// measured vs ~404 modeled in phase 1) is unexplained; further single-lever
// edits were regressing, so R9 stands.
#define TINY_ 1e-40f
#define LOG2E_ 1.4426950408889634f
#define LN2_   0.6931471805599453f

__device__ __forceinline__ float exp2_hw(float x) {
#if __has_builtin(__builtin_amdgcn_exp2f)
    return __builtin_amdgcn_exp2f(x);
#else
    return __expf(x * LN2_);
#endif
}
__device__ __forceinline__ float log2_hw(float x) {
#if __has_builtin(__builtin_amdgcn_logf)
    return __builtin_amdgcn_logf(x);
#else
    return __logf(x) * LOG2E_;
#endif
}
__device__ __forceinline__ float rcp_hw(float x) {
#if __has_builtin(__builtin_amdgcn_rcpf)
    return __builtin_amdgcn_rcpf(x);
#else
    return 1.0f / x;
#endif
}

// ---- DPP helpers (proven in prior rounds) ----
template <int CTRL>
__device__ __forceinline__ float dpp_ident(float identity, float x) {
    return __int_as_float(__builtin_amdgcn_update_dpp(
        __float_as_int(identity), __float_as_int(x), CTRL, 0xF, 0xF, false));
}
__device__ __forceinline__ float readlane63(float x) {
    return __int_as_float(__builtin_amdgcn_readlane(__float_as_int(x), 63));
}
__device__ __forceinline__ float wave_sum_bcast(float s) {
    s += dpp_ident<0x111>(0.f, s);
    s += dpp_ident<0x112>(0.f, s);
    s += dpp_ident<0x114>(0.f, s);
    s += dpp_ident<0x118>(0.f, s);
    s += dpp_ident<0x142>(0.f, s);
    s += dpp_ident<0x143>(0.f, s);
    return readlane63(s);
}
__device__ __forceinline__ float wave_max_bcast(float m) {
    const float NI = __int_as_float(0xff800000);
    m = fmaxf(m, dpp_ident<0x111>(NI, m));
    m = fmaxf(m, dpp_ident<0x112>(NI, m));
    m = fmaxf(m, dpp_ident<0x114>(NI, m));
    m = fmaxf(m, dpp_ident<0x118>(NI, m));
    m = fmaxf(m, dpp_ident<0x142>(NI, m));
    m = fmaxf(m, dpp_ident<0x143>(NI, m));
    return readlane63(m);
}

#define STRIDE_ 9   // 9 coprime 32 -> 2 lanes/bank on row reads/writes (free)

__global__ __launch_bounds__(448) void sinkhorn_kernel(
    const float* __restrict__ theta,  // [64,7]
    const float* __restrict__ phi,    // [7]
    const float* __restrict__ n,      // [64]
    const float* __restrict__ sens,   // [64]
    const float* __restrict__ err,    // [7]
    float* __restrict__ out)          // [64,7]
{
    const int tid  = threadIdx.x;
    const int lane = tid & 63;        // row
    const int wid  = tid >> 6;        // column 0..6 (one wave per column)

    __shared__ float bufEA[2][64 * STRIDE_ + 8];   // exp2(a) per cell
    __shared__ float bufAA[2][64 * STRIDE_ + 8];   // a per cell (rescue)
    __shared__ float ldsS[8];                      // epilogue column sums

    const float ni = n[lane];
    const float si = sens[lane];
    const float ej = err[wid];
    const float th = theta[lane * NB + wid];

    // nsum identical in every wave (same per-lane ni, same tree).
    const float nsum   = wave_sum_bcast(ni);
    const float aT     = ni / nsum + TINY_;
    const float log_a2 = log2_hw(aT);

    // softmax(phi): same scalar sequence as R2/R7.
    float t2v0 = phi[0] * LOG2E_, t2v1 = phi[1] * LOG2E_,
          t2v2 = phi[2] * LOG2E_, t2v3 = phi[3] * LOG2E_,
          t2v4 = phi[4] * LOG2E_, t2v5 = phi[5] * LOG2E_,
          t2v6 = phi[6] * LOG2E_;
    float pmax = t2v0;
    pmax = fmaxf(pmax, t2v1); pmax = fmaxf(pmax, t2v2);
    pmax = fmaxf(pmax, t2v3); pmax = fmaxf(pmax, t2v4);
    pmax = fmaxf(pmax, t2v5); pmax = fmaxf(pmax, t2v6);
    float psum = exp2_hw(t2v0 - pmax);
    psum += exp2_hw(t2v1 - pmax); psum += exp2_hw(t2v2 - pmax);
    psum += exp2_hw(t2v3 - pmax); psum += exp2_hw(t2v4 - pmax);
    psum += exp2_hw(t2v5 - pmax); psum += exp2_hw(t2v6 - pmax);
    const float lps  = log2_hw(psum);
    const float myt2 = phi[wid] * LOG2E_;
    const float bTj  = exp2_hw(myt2 - pmax - lps) + TINY_;
    const float lb2j = log2_hw(bTj);
    const float cbj  = lb2j - log_a2;

    const float kscale = LOG2E_ / EPS_;
    float t = (th - ni * si * ej) * kscale - lb2j;

    const float LOF = __int_as_float(0x0D800000);  // 2^-100
    const float HIF = __int_as_float(0x71800000);  // 2^+100
    const unsigned LOu = 0x0D800000u, HIu = 0x71800000u;
    const int   base = lane * STRIDE_ + wid;
    const int   rb   = lane * STRIDE_;

    // ---- Phase 1: log-domain, transposed. 1 barrier/iter (parity dbuf). ----
    for (int it = 0; it < ITERS1_; ++it) {
        const int p = it & 1;
        const float a = t + cbj;
        bufEA[p][base] = exp2_hw(a);
        bufAA[p][base] = a;
        __syncthreads();

        const float e0 = bufEA[p][rb + 0], e1 = bufEA[p][rb + 1],
                    e2 = bufEA[p][rb + 2], e3 = bufEA[p][rb + 3],
                    e4 = bufEA[p][rb + 4], e5 = bufEA[p][rb + 5],
                    e6 = bufEA[p][rb + 6];
        const float s = ((e0 + e1) + (e2 + e3)) + ((e4 + e5) + e6);

        // Speculative fast-path L; ballot resolves in parallel, rescue
        // overwrites. Same values as R7 (pure scheduling change).
        float L = log2_hw(s);
        const bool ok = (s >= LOF) && (s <= HIF);   // NaN/inf -> false
        if (__ballot(ok) != ~0ull) {                // identical in all waves
            const float a0 = bufAA[p][rb + 0], a1 = bufAA[p][rb + 1],
                        a2 = bufAA[p][rb + 2], a3 = bufAA[p][rb + 3],
                        a4 = bufAA[p][rb + 4], a5 = bufAA[p][rb + 5],
                        a6 = bufAA[p][rb + 6];
            const float m = fmaxf(fmaxf(fmaxf(a0, a1), fmaxf(a2, a3)),
                                  fmaxf(fmaxf(a4, a5), a6));
            const float s2 = ((exp2_hw(a0 - m) + exp2_hw(a1 - m))
                            + (exp2_hw(a2 - m) + exp2_hw(a3 - m)))
                           + ((exp2_hw(a4 - m) + exp2_hw(a5 - m))
                            + exp2_hw(a6 - m));
            L = m + log2_hw(s2);
        }

        const float q = t - L;
        const float e = exp2_hw(q);
        const float ss = wave_sum_bcast(e);         // wave-uniform (SGPR)

        // Speculative fast-path L2; uint window check on the SGPR value
        // (equivalent to float check for >=0 sums; NaN/inf/0 -> rescue).
        float L2 = log2_hw(ss);
        const unsigned ssu = __float_as_uint(ss);
        if (ssu < LOu || ssu > HIu) {               // wave-local decision
            const float M   = wave_max_bcast(q);
            const float e2  = exp2_hw(q - M);
            const float ss2 = wave_sum_bcast(e2);   // in [1,64]
            L2 = M + log2_hw(ss2);
        }
        t = q - L2;
    }

    // ---- Switch @120 (R13-validated mechanics): U = 2^t, underflow->0. ----
    float U = exp2_hw(t);
    const float Bj = exp2_hw(cbj);

    // ---- Phase 2: multiplicative, transposed. 1 barrier/iter. ----
    for (int it2 = 0; it2 < ITERS2_; ++it2) {
        const int p = it2 & 1;
        bufEA[p][base] = U * Bj;
        __syncthreads();
        const float p0 = bufEA[p][rb + 0], p1 = bufEA[p][rb + 1],
                    p2 = bufEA[p][rb + 2], p3 = bufEA[p][rb + 3],
                    p4 = bufEA[p][rb + 4], p5 = bufEA[p][rb + 5],
                    p6 = bufEA[p][rb + 6];
        const float s  = ((p0 + p1) + (p2 + p3)) + ((p4 + p5) + p6);
        const float rs = rcp_hw(s);
        const float w  = U * rs;
        const float ss = wave_sum_bcast(w);
        U = w * rcp_hw(ss);
    }

    // ---- Epilogue: P = U*bT; normalize by total (+TINY). ----
    const float pr = U * bTj;
    const float cs = wave_sum_bcast(pr);   // column sum (wave-uniform)
    if (lane == 0) ldsS[wid] = cs;
    __syncthreads();
    const float total = ((ldsS[0] + ldsS[1]) + (ldsS[2] + ldsS[3]))
                      + ((ldsS[4] + ldsS[5]) + ldsS[6]);
    out[lane * NB + wid] = pr * (1.0f / (total + TINY_));
}

extern "C" void kernel_launch(void* const* d_in, const int* in_sizes, int n_in,
                              void* d_out, int out_size, void* d_ws, size_t ws_size,
                              hipStream_t stream) {
    const float* theta = (const float*)d_in[0];
    const float* phi   = (const float*)d_in[1];
    const float* n     = (const float*)d_in[2];
    const float* sens  = (const float*)d_in[3];
    const float* err   = (const float*)d_in[4];
    float* out = (float*)d_out;

    sinkhorn_kernel<<<1, 448, 0, stream>>>(theta, phi, n, sens, err, out);
}